// Round 7
// baseline (331.765 us; speedup 1.0000x reference)
//
#include <hip/hip_runtime.h>

#define D 128
#define BN_EPS 1e-5f
#define CHUNK 4096   // edges per block in bucket passes (256 thr x 16)

// RNE-pack two f32 into a bf16 pair (lo = element 0, hi = element 1)
__device__ __forceinline__ unsigned bf16pair(float a, float b) {
    unsigned ua = __float_as_uint(a), ub = __float_as_uint(b);
    ua += 0x7fff + ((ua >> 16) & 1);
    ub += 0x7fff + ((ub >> 16) & 1);
    return (ua >> 16) | (ub & 0xffff0000u);
}

// ---------------- P1: bucket histogram (bucket = dst >> 8) ----------------
__global__ __launch_bounds__(256) void k_bhist(const int* __restrict__ dst,
                                               int* __restrict__ bcnt, int E, int nb) {
    __shared__ int h[256];
    int tid = threadIdx.x;
    h[tid] = 0;
    __syncthreads();
    int base = blockIdx.x * CHUNK + tid;
#pragma unroll
    for (int k = 0; k < 16; k++) {
        int i = base + k * 256;
        if (i < E) atomicAdd(&h[dst[i] >> 8], 1);
    }
    __syncthreads();
    if (tid < nb && h[tid]) atomicAdd(&bcnt[tid], h[tid]);
}

// ---------------- P2: scan bucket counts -> bases + cursors (also zeros sums) ----------------
__global__ __launch_bounds__(256) void k_bscan(const int* __restrict__ bcnt,
                                               int* __restrict__ bbase,
                                               int* __restrict__ bcur,
                                               float* __restrict__ sums,
                                               int nb, int E) {
    __shared__ int sh[256];
    int tid = threadIdx.x;
    sums[tid] = 0.f;   // 256 floats: colsum + colsumsq for BN
    int v = (tid < nb) ? bcnt[tid] : 0;
    sh[tid] = v;
    __syncthreads();
    for (int off = 1; off < 256; off <<= 1) {
        int u = (tid >= off) ? sh[tid - off] : 0;
        __syncthreads();
        sh[tid] += u;
        __syncthreads();
    }
    if (tid < nb) {
        bbase[tid] = sh[tid] - v;
        bcur[tid] = sh[tid] - v;
    }
    if (tid == 0) bbase[nb] = E;
}

// ---------------- P3: bucket scatter of (src,dst) pairs, run-coalesced ----------------
__global__ __launch_bounds__(256) void k_bscatter(const int* __restrict__ src,
                                                  const int* __restrict__ dst,
                                                  int* __restrict__ bcur,
                                                  int2* __restrict__ bpairs,
                                                  int E, int nb) {
    __shared__ int h[256];
    int tid = threadIdx.x;
    h[tid] = 0;
    __syncthreads();
    int base = blockIdx.x * CHUNK + tid;
    int s[16], t[16], r[16];
#pragma unroll
    for (int k = 0; k < 16; k++) {
        int i = base + k * 256;
        if (i < E) {
            s[k] = src[i];
            t[k] = dst[i];
            r[k] = atomicAdd(&h[t[k] >> 8], 1);
        } else {
            t[k] = -1;
        }
    }
    __syncthreads();
    if (tid < nb) {
        int c = h[tid];
        h[tid] = c ? atomicAdd(&bcur[tid], c) : 0;
    }
    __syncthreads();
#pragma unroll
    for (int k = 0; k < 16; k++) {
        if (t[k] >= 0) bpairs[h[t[k] >> 8] + r[k]] = make_int2(s[k], t[k]);
    }
}

// ---------------- P4: per-bucket CSR finalize (rowptr, dinv, csr) ----------------
__global__ __launch_bounds__(256) void k_csr(const int2* __restrict__ bpairs,
                                             const int* __restrict__ bbase,
                                             int* __restrict__ rowptr,
                                             int* __restrict__ csr,
                                             float* __restrict__ dinv,
                                             int n, int nb, int E) {
    int b = blockIdx.x;
    int tid = threadIdx.x;
    int lo = bbase[b], hi = bbase[b + 1];
    __shared__ int h[256];
    __shared__ int sh[256];
    h[tid] = 0;
    __syncthreads();
    for (int i = lo + tid; i < hi; i += 256) atomicAdd(&h[bpairs[i].y & 255], 1);
    __syncthreads();
    int c = h[tid];
    sh[tid] = c;
    __syncthreads();
    for (int off = 1; off < 256; off <<= 1) {
        int u = (tid >= off) ? sh[tid - off] : 0;
        __syncthreads();
        sh[tid] += u;
        __syncthreads();
    }
    int ex = sh[tid] - c;
    int row = b * 256 + tid;
    if (row < n) {
        rowptr[row] = lo + ex;
        dinv[row] = rsqrtf((float)(c + 1));   // +1 = self loop
    }
    if (b == 0 && tid == 0) rowptr[n] = E;
    __syncthreads();
    h[tid] = lo + ex;   // reuse as cursor
    __syncthreads();
    for (int i = lo + tid; i < hi; i += 256) {
        int2 p = bpairs[i];
        int pos = atomicAdd(&h[p.y & 255], 1);
        csr[pos] = p.x;
    }
}

// ---------------- gather aggregation (grid-stride, optional BN stats / bias) -----
// Hb[s] = bf16(dinv[s]*h[s])  (pre-scaled payload; self term is Hb[row] too)
// OUT[t] = ( Hb[t] + sum_{s in N(t)} Hb[s] ) * dinv[t] + bias
// If sums != null: accumulate per-column sum/sumsq of OUT into sums[0:128]/sums[128:256]
__global__ __launch_bounds__(256) void k_agg(const unsigned* __restrict__ Hb,
                                             const int* __restrict__ csr_src,
                                             const int* __restrict__ rowptr,
                                             const float* __restrict__ dinv,
                                             const float* __restrict__ bias,
                                             float* __restrict__ sums,
                                             float* __restrict__ OUT, int n) {
    int wave = threadIdx.x >> 6, lane = threadIdx.x & 63;
    float s0 = 0.f, s1 = 0.f, q0 = 0.f, q1 = 0.f;
    for (int row = blockIdx.x * 4 + wave; row < n; row += gridDim.x * 4) {
        unsigned us = Hb[(size_t)row * 64 + lane];           // bf16 self term
        float ax = __uint_as_float(us << 16);
        float ay = __uint_as_float(us & 0xffff0000u);
        int k0 = rowptr[row], k1 = rowptr[row + 1];
        int k = k0;
        for (; k + 4 <= k1; k += 4) {
            int i0 = csr_src[k], i1 = csr_src[k + 1];
            int i2 = csr_src[k + 2], i3 = csr_src[k + 3];
            unsigned u0 = Hb[(size_t)i0 * 64 + lane];
            unsigned u1 = Hb[(size_t)i1 * 64 + lane];
            unsigned u2 = Hb[(size_t)i2 * 64 + lane];
            unsigned u3 = Hb[(size_t)i3 * 64 + lane];
            ax += __uint_as_float(u0 << 16);
            ay += __uint_as_float(u0 & 0xffff0000u);
            ax += __uint_as_float(u1 << 16);
            ay += __uint_as_float(u1 & 0xffff0000u);
            ax += __uint_as_float(u2 << 16);
            ay += __uint_as_float(u2 & 0xffff0000u);
            ax += __uint_as_float(u3 << 16);
            ay += __uint_as_float(u3 & 0xffff0000u);
        }
        for (; k < k1; k++) {
            unsigned u = Hb[(size_t)csr_src[k] * 64 + lane];
            ax += __uint_as_float(u << 16);
            ay += __uint_as_float(u & 0xffff0000u);
        }
        float dt = dinv[row];
        ax *= dt;
        ay *= dt;
        if (bias) {
            float2 b = ((const float2*)bias)[lane];
            ax += b.x;
            ay += b.y;
        }
        ((float2*)OUT)[(size_t)row * 64 + lane] = make_float2(ax, ay);
        if (sums) {
            s0 += ax; q0 += ax * ax;
            s1 += ay; q1 += ay * ay;
        }
    }
    if (sums) {
        __shared__ float4 red[4][64];
        red[wave][lane] = make_float4(s0, s1, q0, q1);
        __syncthreads();
        if (wave == 0) {
            float4 a = red[0][lane], b = red[1][lane];
            float4 c = red[2][lane], d = red[3][lane];
            atomicAdd(&sums[lane * 2 + 0], a.x + b.x + c.x + d.x);
            atomicAdd(&sums[lane * 2 + 1], a.y + b.y + c.y + d.y);
            atomicAdd(&sums[D + lane * 2 + 0], a.z + b.z + c.z + d.z);
            atomicAdd(&sums[D + lane * 2 + 1], a.w + b.w + c.w + d.w);
        }
    }
}

// ---------------- tiled GEMM: Yb = bf16(dinv .* (f(X) @ W)) ----------------
// 64 rows/block, 128 threads, 8x8 thread tile (LDS/FMA balanced at 1 B/FMA).
// f = identity if sc==null, else relu(x*scale + shift), sc[0:128]=scale, sc[128:256]=shift
#define XS_STRIDE 68
__global__ __launch_bounds__(128) void k_gemm(const float* __restrict__ X,
                                              const float* __restrict__ W,
                                              const float* __restrict__ sc,
                                              const float* __restrict__ dinv,
                                              unsigned* __restrict__ Yb, int n) {
    __shared__ float XsT[32 * XS_STRIDE];   // [kk][row], transposed chunk
    __shared__ float Ws[32 * 132];          // [kk][c], padded stride
    int tid = threadIdx.x;
    int row0 = blockIdx.x * 64;
    int rg = tid & 7;    // rows rg*8 .. rg*8+7
    int cg = tid >> 3;   // cols cg*8 .. cg*8+7  (16 colgroups)
    float acc[8][8];
#pragma unroll
    for (int i = 0; i < 8; i++)
#pragma unroll
        for (int j = 0; j < 8; j++) acc[i][j] = 0.f;

    for (int kc = 0; kc < 4; kc++) {
        __syncthreads();
        // stage W chunk (32 k x 128 c) = 1024 float4, 8 per thread
        {
#pragma unroll
            for (int p = 0; p < 8; p++) {
                int idx = tid + p * 128;
                int k = idx >> 5, c4 = idx & 31;
                float4 w = ((const float4*)(W + (size_t)(kc * 32 + k) * D))[c4];
                *(float4*)&Ws[k * 132 + c4 * 4] = w;
            }
        }
        // stage X chunk transposed (64 rows x 32 k), optional BN+ReLU on load
        {
#pragma unroll
            for (int p = 0; p < 4; p++) {
                int idx = tid + p * 128;
                int r = idx >> 3, kq = idx & 7;
                int grow = row0 + r;
                float4 v = make_float4(0.f, 0.f, 0.f, 0.f);
                if (grow < n)
                    v = *(const float4*)(X + (size_t)grow * D + kc * 32 + kq * 4);
                if (sc) {
                    int c4 = kc * 8 + kq;
                    float4 scl = ((const float4*)sc)[c4];
                    float4 sh  = ((const float4*)(sc + D))[c4];
                    v.x = fmaxf(fmaf(v.x, scl.x, sh.x), 0.f);
                    v.y = fmaxf(fmaf(v.y, scl.y, sh.y), 0.f);
                    v.z = fmaxf(fmaf(v.z, scl.z, sh.z), 0.f);
                    v.w = fmaxf(fmaf(v.w, scl.w, sh.w), 0.f);
                }
                XsT[(kq * 4 + 0) * XS_STRIDE + r] = v.x;
                XsT[(kq * 4 + 1) * XS_STRIDE + r] = v.y;
                XsT[(kq * 4 + 2) * XS_STRIDE + r] = v.z;
                XsT[(kq * 4 + 3) * XS_STRIDE + r] = v.w;
            }
        }
        __syncthreads();
#pragma unroll 2
        for (int kk = 0; kk < 32; kk++) {
            float xr[8], wc[8];
            *(float4*)&xr[0] = *(const float4*)&XsT[kk * XS_STRIDE + rg * 8];
            *(float4*)&xr[4] = *(const float4*)&XsT[kk * XS_STRIDE + rg * 8 + 4];
            *(float4*)&wc[0] = *(const float4*)&Ws[kk * 132 + cg * 8];
            *(float4*)&wc[4] = *(const float4*)&Ws[kk * 132 + cg * 8 + 4];
#pragma unroll
            for (int i = 0; i < 8; i++)
#pragma unroll
                for (int j = 0; j < 8; j++)
                    acc[i][j] = fmaf(xr[i], wc[j], acc[i][j]);
        }
    }
#pragma unroll
    for (int i = 0; i < 8; i++) {
        int grow = row0 + rg * 8 + i;
        if (grow < n) {
            float dt = dinv[grow];
            uint4 pk;
            pk.x = bf16pair(dt * acc[i][0], dt * acc[i][1]);
            pk.y = bf16pair(dt * acc[i][2], dt * acc[i][3]);
            pk.z = bf16pair(dt * acc[i][4], dt * acc[i][5]);
            pk.w = bf16pair(dt * acc[i][6], dt * acc[i][7]);
            ((uint4*)Yb)[(size_t)grow * 16 + cg] = pk;
        }
    }
}

// sc[0:128]=scale, sc[128:256]=shift.  (b1 cancels exactly in BN — omitted.)
__global__ __launch_bounds__(128) void k_bn_finalize(const float* __restrict__ sums,
                                                     const float* __restrict__ gamma,
                                                     const float* __restrict__ beta,
                                                     float* __restrict__ sc, int n) {
    int j = threadIdx.x;
    float inv_n = 1.0f / (float)n;
    float mu = sums[j] * inv_n;
    float var = sums[D + j] * inv_n - mu * mu;
    float is = rsqrtf(var + BN_EPS);
    float scale = gamma[j] * is;
    sc[j] = scale;
    sc[D + j] = beta[j] - mu * scale;
}

extern "C" void kernel_launch(void* const* d_in, const int* in_sizes, int n_in,
                              void* d_out, int out_size, void* d_ws, size_t ws_size,
                              hipStream_t stream) {
    const float* x     = (const float*)d_in[0];
    const int*   ei    = (const int*)d_in[1];
    const float* W1    = (const float*)d_in[2];
    // d_in[3] = b1 — cancels exactly in BatchNorm, unused
    const float* gamma = (const float*)d_in[4];
    const float* beta  = (const float*)d_in[5];
    const float* W2    = (const float*)d_in[6];
    const float* b2    = (const float*)d_in[7];
    float* out = (float*)d_out;

    int n = in_sizes[0] / D;   // 50000
    int E = in_sizes[1] / 2;   // 800000
    const int* src = ei;
    const int* dst = ei + E;
    int nb = (n + 255) >> 8;          // 196 buckets (must be <= 256)
    int nchunks = (E + CHUNK - 1) / CHUNK;

    char* ws = (char*)d_ws;
    size_t off = 0;
    auto alloc = [&](size_t bytes) {
        char* p = ws + off;
        off = (off + bytes + 511) & ~(size_t)511;
        return p;
    };
    size_t szH = (size_t)n * D * sizeof(float);
    float*    agg    = (float*)alloc(szH);                       // conv1 agg / BN input
    unsigned* hbf    = (unsigned*)alloc((size_t)n * D * 2);      // bf16 pre-scaled payload
    float*    dinv   = (float*)alloc(n * sizeof(float));
    int*      rowptr = (int*)alloc((n + 1) * sizeof(int));
    int*      bcnt   = (int*)alloc(256 * sizeof(int));
    int*      bbase  = (int*)alloc(257 * sizeof(int));
    int*      bcur   = (int*)alloc(256 * sizeof(int));
    int2*     bpairs = (int2*)alloc((size_t)E * sizeof(int2));
    int*      csr    = (int*)alloc((size_t)E * sizeof(int));
    float*    sums   = (float*)alloc(2 * D * sizeof(float));
    float*    sc     = (float*)alloc(2 * D * sizeof(float));

    hipMemsetAsync(bcnt, 0, 256 * sizeof(int), stream);

    // CSR build: bucket hist -> bucket scan (+zero sums) -> pair scatter -> finalize
    k_bhist<<<nchunks, 256, 0, stream>>>(dst, bcnt, E, nb);
    k_bscan<<<1, 256, 0, stream>>>(bcnt, bbase, bcur, sums, nb, E);
    k_bscatter<<<nchunks, 256, 0, stream>>>(src, dst, bcur, bpairs, E, nb);
    k_csr<<<nb, 256, 0, stream>>>(bpairs, bbase, rowptr, csr, dinv, n, nb, E);

    // conv1: hbf = bf16(dinv .* (x@W1)); agg = aggregate(hbf) with fused BN stats
    k_gemm<<<(n + 63) / 64, 128, 0, stream>>>(x, W1, nullptr, dinv, hbf, n);
    k_agg<<<784, 256, 0, stream>>>(hbf, csr, rowptr, dinv, nullptr, sums, agg, n);

    // BN scale/shift (ReLU fused into GEMM2 load)
    k_bn_finalize<<<1, 128, 0, stream>>>(sums, gamma, beta, sc, n);

    // conv2: hbf = bf16(dinv .* (relu(BN(agg))@W2)); out = aggregate(hbf) + b2
    k_gemm<<<(n + 63) / 64, 128, 0, stream>>>(agg, W2, sc, dinv, hbf, n);
    k_agg<<<(n + 3) / 4, 256, 0, stream>>>(hbf, csr, rowptr, dinv, b2, nullptr, out, n);
}

// Round 8
// 307.652 us; speedup vs baseline: 1.0784x; 1.0784x over previous
//
#include <hip/hip_runtime.h>

#define D 128
#define BN_EPS 1e-5f
#define CHUNK 4096   // edges per block in bucket passes (256 thr x 16)

// RNE-pack two f32 into a bf16 pair (lo = element 0, hi = element 1)
__device__ __forceinline__ unsigned bf16pair(float a, float b) {
    unsigned ua = __float_as_uint(a), ub = __float_as_uint(b);
    ua += 0x7fff + ((ua >> 16) & 1);
    ub += 0x7fff + ((ub >> 16) & 1);
    return (ua >> 16) | (ub & 0xffff0000u);
}

// ---------------- P1: bucket histogram (bucket = dst >> 8) ----------------
__global__ __launch_bounds__(256) void k_bhist(const int* __restrict__ dst,
                                               int* __restrict__ bcnt, int E, int nb) {
    __shared__ int h[256];
    int tid = threadIdx.x;
    h[tid] = 0;
    __syncthreads();
    int base = blockIdx.x * CHUNK + tid;
#pragma unroll
    for (int k = 0; k < 16; k++) {
        int i = base + k * 256;
        if (i < E) atomicAdd(&h[dst[i] >> 8], 1);
    }
    __syncthreads();
    if (tid < nb && h[tid]) atomicAdd(&bcnt[tid], h[tid]);
}

// ---------------- P2: scan bucket counts -> bases + cursors (also zeros sums) --------
__global__ __launch_bounds__(256) void k_bscan(const int* __restrict__ bcnt,
                                               int* __restrict__ bbase,
                                               int* __restrict__ bcur,
                                               float* __restrict__ sums,
                                               int nb, int E) {
    __shared__ int sh[256];
    int tid = threadIdx.x;
    sums[tid] = 0.f;   // 256 floats: colsum + colsumsq for BN
    int v = (tid < nb) ? bcnt[tid] : 0;
    sh[tid] = v;
    __syncthreads();
    for (int off = 1; off < 256; off <<= 1) {
        int u = (tid >= off) ? sh[tid - off] : 0;
        __syncthreads();
        sh[tid] += u;
        __syncthreads();
    }
    if (tid < nb) {
        bbase[tid] = sh[tid] - v;
        bcur[tid] = sh[tid] - v;
    }
    if (tid == 0) bbase[nb] = E;
}

// ---------------- P3: bucket scatter of (src,dst) pairs, run-coalesced ----------------
__global__ __launch_bounds__(256) void k_bscatter(const int* __restrict__ src,
                                                  const int* __restrict__ dst,
                                                  int* __restrict__ bcur,
                                                  int2* __restrict__ bpairs,
                                                  int E, int nb) {
    __shared__ int h[256];
    int tid = threadIdx.x;
    h[tid] = 0;
    __syncthreads();
    int base = blockIdx.x * CHUNK + tid;
    int s[16], t[16], r[16];
#pragma unroll
    for (int k = 0; k < 16; k++) {
        int i = base + k * 256;
        if (i < E) {
            s[k] = src[i];
            t[k] = dst[i];
            r[k] = atomicAdd(&h[t[k] >> 8], 1);
        } else {
            t[k] = -1;
        }
    }
    __syncthreads();
    if (tid < nb) {
        int c = h[tid];
        h[tid] = c ? atomicAdd(&bcur[tid], c) : 0;
    }
    __syncthreads();
#pragma unroll
    for (int k = 0; k < 16; k++) {
        if (t[k] >= 0) bpairs[h[t[k] >> 8] + r[k]] = make_int2(s[k], t[k]);
    }
}

// ---------------- P4: per-bucket CSR finalize (rowptr, dinv, csr) ----------------
__global__ __launch_bounds__(256) void k_csr(const int2* __restrict__ bpairs,
                                             const int* __restrict__ bbase,
                                             int* __restrict__ rowptr,
                                             int* __restrict__ csr,
                                             float* __restrict__ dinv,
                                             int n, int nb, int E) {
    int b = blockIdx.x;
    int tid = threadIdx.x;
    int lo = bbase[b], hi = bbase[b + 1];
    __shared__ int h[256];
    __shared__ int sh[256];
    h[tid] = 0;
    __syncthreads();
    for (int i = lo + tid; i < hi; i += 256) atomicAdd(&h[bpairs[i].y & 255], 1);
    __syncthreads();
    int c = h[tid];
    sh[tid] = c;
    __syncthreads();
    for (int off = 1; off < 256; off <<= 1) {
        int u = (tid >= off) ? sh[tid - off] : 0;
        __syncthreads();
        sh[tid] += u;
        __syncthreads();
    }
    int ex = sh[tid] - c;
    int row = b * 256 + tid;
    if (row < n) {
        rowptr[row] = lo + ex;
        dinv[row] = rsqrtf((float)(c + 1));   // +1 = self loop
    }
    if (b == 0 && tid == 0) rowptr[n] = E;
    __syncthreads();
    h[tid] = lo + ex;   // reuse as cursor
    __syncthreads();
    for (int i = lo + tid; i < hi; i += 256) {
        int2 p = bpairs[i];
        int pos = atomicAdd(&h[p.y & 255], 1);
        csr[pos] = p.x;
    }
}

// ---------------- gather aggregation: one wave per output row ----------------
// Hb[s] = bf16(dinv[s]*h[s])  (pre-scaled payload; self term is Hb[row] too)
// OUT[t] = ( Hb[t] + sum_{s in N(t)} Hb[s] ) * dinv[t] + bias
__global__ __launch_bounds__(256) void k_agg(const unsigned* __restrict__ Hb,
                                             const int* __restrict__ csr_src,
                                             const int* __restrict__ rowptr,
                                             const float* __restrict__ dinv,
                                             const float* __restrict__ bias,
                                             float* __restrict__ OUT, int n) {
    int row = blockIdx.x * 4 + (threadIdx.x >> 6);
    if (row >= n) return;
    int lane = threadIdx.x & 63;
    unsigned us = Hb[(size_t)row * 64 + lane];           // bf16 self term
    float ax = __uint_as_float(us << 16);
    float ay = __uint_as_float(us & 0xffff0000u);
    int k0 = rowptr[row], k1 = rowptr[row + 1];
    int k = k0;
    for (; k + 4 <= k1; k += 4) {
        int i0 = csr_src[k], i1 = csr_src[k + 1];
        int i2 = csr_src[k + 2], i3 = csr_src[k + 3];
        unsigned u0 = Hb[(size_t)i0 * 64 + lane];
        unsigned u1 = Hb[(size_t)i1 * 64 + lane];
        unsigned u2 = Hb[(size_t)i2 * 64 + lane];
        unsigned u3 = Hb[(size_t)i3 * 64 + lane];
        ax += __uint_as_float(u0 << 16);
        ay += __uint_as_float(u0 & 0xffff0000u);
        ax += __uint_as_float(u1 << 16);
        ay += __uint_as_float(u1 & 0xffff0000u);
        ax += __uint_as_float(u2 << 16);
        ay += __uint_as_float(u2 & 0xffff0000u);
        ax += __uint_as_float(u3 << 16);
        ay += __uint_as_float(u3 & 0xffff0000u);
    }
    for (; k < k1; k++) {
        unsigned u = Hb[(size_t)csr_src[k] * 64 + lane];
        ax += __uint_as_float(u << 16);
        ay += __uint_as_float(u & 0xffff0000u);
    }
    float dt = dinv[row];
    ax *= dt;
    ay *= dt;
    if (bias) {
        float2 b = ((const float2*)bias)[lane];
        ax += b.x;
        ay += b.y;
    }
    ((float2*)OUT)[(size_t)row * 64 + lane] = make_float2(ax, ay);
}

// ---------------- tiled GEMM: Yb = bf16(dinv .* (f(X) @ W)) ----------------
// 64 rows/block, 128 threads, 8x8 thread tile (LDS/FMA balanced at 1 B/FMA).
// f = identity if sc==null, else relu(x*scale + shift), sc[0:128]=scale, sc[128:256]=shift
#define XS_STRIDE 68
__global__ __launch_bounds__(128) void k_gemm(const float* __restrict__ X,
                                              const float* __restrict__ W,
                                              const float* __restrict__ sc,
                                              const float* __restrict__ dinv,
                                              unsigned* __restrict__ Yb, int n) {
    __shared__ float XsT[32 * XS_STRIDE];   // [kk][row], transposed chunk
    __shared__ float Ws[32 * 132];          // [kk][c], padded stride
    int tid = threadIdx.x;
    int row0 = blockIdx.x * 64;
    int rg = tid & 7;    // rows rg*8 .. rg*8+7
    int cg = tid >> 3;   // cols cg*8 .. cg*8+7  (16 colgroups)
    float acc[8][8];
#pragma unroll
    for (int i = 0; i < 8; i++)
#pragma unroll
        for (int j = 0; j < 8; j++) acc[i][j] = 0.f;

    for (int kc = 0; kc < 4; kc++) {
        __syncthreads();
        // stage W chunk (32 k x 128 c) = 1024 float4, 8 per thread
        {
#pragma unroll
            for (int p = 0; p < 8; p++) {
                int idx = tid + p * 128;
                int k = idx >> 5, c4 = idx & 31;
                float4 w = ((const float4*)(W + (size_t)(kc * 32 + k) * D))[c4];
                *(float4*)&Ws[k * 132 + c4 * 4] = w;
            }
        }
        // stage X chunk transposed (64 rows x 32 k), optional BN+ReLU on load
        {
#pragma unroll
            for (int p = 0; p < 4; p++) {
                int idx = tid + p * 128;
                int r = idx >> 3, kq = idx & 7;
                int grow = row0 + r;
                float4 v = make_float4(0.f, 0.f, 0.f, 0.f);
                if (grow < n)
                    v = *(const float4*)(X + (size_t)grow * D + kc * 32 + kq * 4);
                if (sc) {
                    int c4 = kc * 8 + kq;
                    float4 scl = ((const float4*)sc)[c4];
                    float4 sh  = ((const float4*)(sc + D))[c4];
                    v.x = fmaxf(fmaf(v.x, scl.x, sh.x), 0.f);
                    v.y = fmaxf(fmaf(v.y, scl.y, sh.y), 0.f);
                    v.z = fmaxf(fmaf(v.z, scl.z, sh.z), 0.f);
                    v.w = fmaxf(fmaf(v.w, scl.w, sh.w), 0.f);
                }
                XsT[(kq * 4 + 0) * XS_STRIDE + r] = v.x;
                XsT[(kq * 4 + 1) * XS_STRIDE + r] = v.y;
                XsT[(kq * 4 + 2) * XS_STRIDE + r] = v.z;
                XsT[(kq * 4 + 3) * XS_STRIDE + r] = v.w;
            }
        }
        __syncthreads();
#pragma unroll 2
        for (int kk = 0; kk < 32; kk++) {
            float xr[8], wc[8];
            *(float4*)&xr[0] = *(const float4*)&XsT[kk * XS_STRIDE + rg * 8];
            *(float4*)&xr[4] = *(const float4*)&XsT[kk * XS_STRIDE + rg * 8 + 4];
            *(float4*)&wc[0] = *(const float4*)&Ws[kk * 132 + cg * 8];
            *(float4*)&wc[4] = *(const float4*)&Ws[kk * 132 + cg * 8 + 4];
#pragma unroll
            for (int i = 0; i < 8; i++)
#pragma unroll
                for (int j = 0; j < 8; j++)
                    acc[i][j] = fmaf(xr[i], wc[j], acc[i][j]);
        }
    }
#pragma unroll
    for (int i = 0; i < 8; i++) {
        int grow = row0 + rg * 8 + i;
        if (grow < n) {
            float dt = dinv[grow];
            uint4 pk;
            pk.x = bf16pair(dt * acc[i][0], dt * acc[i][1]);
            pk.y = bf16pair(dt * acc[i][2], dt * acc[i][3]);
            pk.z = bf16pair(dt * acc[i][4], dt * acc[i][5]);
            pk.w = bf16pair(dt * acc[i][6], dt * acc[i][7]);
            ((uint4*)Yb)[(size_t)grow * 16 + cg] = pk;
        }
    }
}

// ---------------- BN stats (512 blocks -> 512-way atomic contention, safe) ----------
__global__ __launch_bounds__(128) void k_bn_stats(const float* __restrict__ A,
                                                  float* __restrict__ sums, int n) {
    int j = threadIdx.x;
    float s = 0.f, ss = 0.f;
    for (int r = blockIdx.x; r < n; r += gridDim.x) {
        float v = A[(size_t)r * D + j];
        s += v;
        ss += v * v;
    }
    atomicAdd(&sums[j], s);
    atomicAdd(&sums[D + j], ss);
}

// sc[0:128]=scale, sc[128:256]=shift.  (b1 cancels exactly in BN — omitted.)
__global__ __launch_bounds__(128) void k_bn_finalize(const float* __restrict__ sums,
                                                     const float* __restrict__ gamma,
                                                     const float* __restrict__ beta,
                                                     float* __restrict__ sc, int n) {
    int j = threadIdx.x;
    float inv_n = 1.0f / (float)n;
    float mu = sums[j] * inv_n;
    float var = sums[D + j] * inv_n - mu * mu;
    float is = rsqrtf(var + BN_EPS);
    float scale = gamma[j] * is;
    sc[j] = scale;
    sc[D + j] = beta[j] - mu * scale;
}

extern "C" void kernel_launch(void* const* d_in, const int* in_sizes, int n_in,
                              void* d_out, int out_size, void* d_ws, size_t ws_size,
                              hipStream_t stream) {
    const float* x     = (const float*)d_in[0];
    const int*   ei    = (const int*)d_in[1];
    const float* W1    = (const float*)d_in[2];
    // d_in[3] = b1 — cancels exactly in BatchNorm, unused
    const float* gamma = (const float*)d_in[4];
    const float* beta  = (const float*)d_in[5];
    const float* W2    = (const float*)d_in[6];
    const float* b2    = (const float*)d_in[7];
    float* out = (float*)d_out;

    int n = in_sizes[0] / D;   // 50000
    int E = in_sizes[1] / 2;   // 800000
    const int* src = ei;
    const int* dst = ei + E;
    int nb = (n + 255) >> 8;          // 196 buckets (must be <= 256)
    int nchunks = (E + CHUNK - 1) / CHUNK;

    char* ws = (char*)d_ws;
    size_t off = 0;
    auto alloc = [&](size_t bytes) {
        char* p = ws + off;
        off = (off + bytes + 511) & ~(size_t)511;
        return p;
    };
    size_t szH = (size_t)n * D * sizeof(float);
    float*    agg    = (float*)alloc(szH);                       // conv1 agg / BN input
    unsigned* hbf    = (unsigned*)alloc((size_t)n * D * 2);      // bf16 pre-scaled payload
    float*    dinv   = (float*)alloc(n * sizeof(float));
    int*      rowptr = (int*)alloc((n + 1) * sizeof(int));
    int*      bcnt   = (int*)alloc(256 * sizeof(int));
    int*      bbase  = (int*)alloc(257 * sizeof(int));
    int*      bcur   = (int*)alloc(256 * sizeof(int));
    int2*     bpairs = (int2*)alloc((size_t)E * sizeof(int2));
    int*      csr    = (int*)alloc((size_t)E * sizeof(int));
    float*    sums   = (float*)alloc(2 * D * sizeof(float));
    float*    sc     = (float*)alloc(2 * D * sizeof(float));

    hipMemsetAsync(bcnt, 0, 256 * sizeof(int), stream);

    // CSR build: bucket hist -> bucket scan (+zero sums) -> pair scatter -> finalize
    k_bhist<<<nchunks, 256, 0, stream>>>(dst, bcnt, E, nb);
    k_bscan<<<1, 256, 0, stream>>>(bcnt, bbase, bcur, sums, nb, E);
    k_bscatter<<<nchunks, 256, 0, stream>>>(src, dst, bcur, bpairs, E, nb);
    k_csr<<<nb, 256, 0, stream>>>(bpairs, bbase, rowptr, csr, dinv, n, nb, E);

    // conv1: hbf = bf16(dinv .* (x@W1)); agg = aggregate(hbf)
    k_gemm<<<(n + 63) / 64, 128, 0, stream>>>(x, W1, nullptr, dinv, hbf, n);
    k_agg<<<(n + 3) / 4, 256, 0, stream>>>(hbf, csr, rowptr, dinv, nullptr, agg, n);

    // BN stats -> scale/shift (ReLU fused into GEMM2 load)
    k_bn_stats<<<512, 128, 0, stream>>>(agg, sums, n);
    k_bn_finalize<<<1, 128, 0, stream>>>(sums, gamma, beta, sc, n);

    // conv2: hbf = bf16(dinv .* (relu(BN(agg))@W2)); out = aggregate(hbf) + b2
    k_gemm<<<(n + 63) / 64, 128, 0, stream>>>(agg, W2, sc, dinv, hbf, n);
    k_agg<<<(n + 3) / 4, 256, 0, stream>>>(hbf, csr, rowptr, dinv, b2, out, n);
}

// Round 9
// 276.782 us; speedup vs baseline: 1.1987x; 1.1115x over previous
//
#include <hip/hip_runtime.h>

#define D 128
#define BN_EPS 1e-5f
#define CHUNK 4096   // edges per block in bucket passes (256 thr x 16)

typedef __attribute__((ext_vector_type(8))) short bf16x8;
typedef __attribute__((ext_vector_type(4))) float f32x4;

// RNE round f32 -> bf16 (returns low 16)
__device__ __forceinline__ unsigned short bf16r(float a) {
    unsigned u = __float_as_uint(a);
    u += 0x7fff + ((u >> 16) & 1);
    return (unsigned short)(u >> 16);
}
// RNE-pack two f32 into bf16 pair (lo = elem0)
__device__ __forceinline__ unsigned bf16pairp(float a, float b) {
    return (unsigned)bf16r(a) | ((unsigned)bf16r(b) << 16);
}

// ---------------- P1: bucket histogram (bucket = dst >> 8) ----------------
__global__ __launch_bounds__(256) void k_bhist(const int* __restrict__ dst,
                                               int* __restrict__ bcnt, int E, int nb) {
    __shared__ int h[256];
    int tid = threadIdx.x;
    h[tid] = 0;
    __syncthreads();
    int base = blockIdx.x * CHUNK + tid;
#pragma unroll
    for (int k = 0; k < 16; k++) {
        int i = base + k * 256;
        if (i < E) atomicAdd(&h[dst[i] >> 8], 1);
    }
    __syncthreads();
    if (tid < nb && h[tid]) atomicAdd(&bcnt[tid], h[tid]);
}

// ---------------- P2: scan bucket counts -> bases + cursors (also zeros sums) --------
__global__ __launch_bounds__(256) void k_bscan(const int* __restrict__ bcnt,
                                               int* __restrict__ bbase,
                                               int* __restrict__ bcur,
                                               float* __restrict__ sums,
                                               int nb, int E) {
    __shared__ int sh[256];
    int tid = threadIdx.x;
    sums[tid] = 0.f;   // 256 floats: colsum + colsumsq for BN
    int v = (tid < nb) ? bcnt[tid] : 0;
    sh[tid] = v;
    __syncthreads();
    for (int off = 1; off < 256; off <<= 1) {
        int u = (tid >= off) ? sh[tid - off] : 0;
        __syncthreads();
        sh[tid] += u;
        __syncthreads();
    }
    if (tid < nb) {
        bbase[tid] = sh[tid] - v;
        bcur[tid] = sh[tid] - v;
    }
    if (tid == 0) bbase[nb] = E;
}

// ---------------- P3: bucket scatter of (src,dst) pairs, run-coalesced ----------------
__global__ __launch_bounds__(256) void k_bscatter(const int* __restrict__ src,
                                                  const int* __restrict__ dst,
                                                  int* __restrict__ bcur,
                                                  int2* __restrict__ bpairs,
                                                  int E, int nb) {
    __shared__ int h[256];
    int tid = threadIdx.x;
    h[tid] = 0;
    __syncthreads();
    int base = blockIdx.x * CHUNK + tid;
    int s[16], t[16], r[16];
#pragma unroll
    for (int k = 0; k < 16; k++) {
        int i = base + k * 256;
        if (i < E) {
            s[k] = src[i];
            t[k] = dst[i];
            r[k] = atomicAdd(&h[t[k] >> 8], 1);
        } else {
            t[k] = -1;
        }
    }
    __syncthreads();
    if (tid < nb) {
        int c = h[tid];
        h[tid] = c ? atomicAdd(&bcur[tid], c) : 0;
    }
    __syncthreads();
#pragma unroll
    for (int k = 0; k < 16; k++) {
        if (t[k] >= 0) bpairs[h[t[k] >> 8] + r[k]] = make_int2(s[k], t[k]);
    }
}

// ---------------- P4: per-bucket CSR finalize (rowptr, dinv, csr) ----------------
__global__ __launch_bounds__(256) void k_csr(const int2* __restrict__ bpairs,
                                             const int* __restrict__ bbase,
                                             int* __restrict__ rowptr,
                                             int* __restrict__ csr,
                                             float* __restrict__ dinv,
                                             int n, int nb, int E) {
    int b = blockIdx.x;
    int tid = threadIdx.x;
    int lo = bbase[b], hi = bbase[b + 1];
    __shared__ int h[256];
    __shared__ int sh[256];
    h[tid] = 0;
    __syncthreads();
    for (int i = lo + tid; i < hi; i += 256) atomicAdd(&h[bpairs[i].y & 255], 1);
    __syncthreads();
    int c = h[tid];
    sh[tid] = c;
    __syncthreads();
    for (int off = 1; off < 256; off <<= 1) {
        int u = (tid >= off) ? sh[tid - off] : 0;
        __syncthreads();
        sh[tid] += u;
        __syncthreads();
    }
    int ex = sh[tid] - c;
    int row = b * 256 + tid;
    if (row < n) {
        rowptr[row] = lo + ex;
        dinv[row] = rsqrtf((float)(c + 1));   // +1 = self loop
    }
    if (b == 0 && tid == 0) rowptr[n] = E;
    __syncthreads();
    h[tid] = lo + ex;   // reuse as cursor
    __syncthreads();
    for (int i = lo + tid; i < hi; i += 256) {
        int2 p = bpairs[i];
        int pos = atomicAdd(&h[p.y & 255], 1);
        csr[pos] = p.x;
    }
}

// ---------------- gather aggregation: one wave per output row ----------------
// Hb[s] = bf16(dinv[s]*h[s])  (pre-scaled payload; self term is Hb[row] too)
// OUT[t] = ( Hb[t] + sum_{s in N(t)} Hb[s] ) * dinv[t] + bias
__global__ __launch_bounds__(256) void k_agg(const unsigned* __restrict__ Hb,
                                             const int* __restrict__ csr_src,
                                             const int* __restrict__ rowptr,
                                             const float* __restrict__ dinv,
                                             const float* __restrict__ bias,
                                             float* __restrict__ OUT, int n) {
    int row = blockIdx.x * 4 + (threadIdx.x >> 6);
    if (row >= n) return;
    int lane = threadIdx.x & 63;
    unsigned us = Hb[(size_t)row * 64 + lane];           // bf16 self term
    float ax = __uint_as_float(us << 16);
    float ay = __uint_as_float(us & 0xffff0000u);
    int k0 = rowptr[row], k1 = rowptr[row + 1];
    int k = k0;
    for (; k + 4 <= k1; k += 4) {
        int i0 = csr_src[k], i1 = csr_src[k + 1];
        int i2 = csr_src[k + 2], i3 = csr_src[k + 3];
        unsigned u0 = Hb[(size_t)i0 * 64 + lane];
        unsigned u1 = Hb[(size_t)i1 * 64 + lane];
        unsigned u2 = Hb[(size_t)i2 * 64 + lane];
        unsigned u3 = Hb[(size_t)i3 * 64 + lane];
        ax += __uint_as_float(u0 << 16);
        ay += __uint_as_float(u0 & 0xffff0000u);
        ax += __uint_as_float(u1 << 16);
        ay += __uint_as_float(u1 & 0xffff0000u);
        ax += __uint_as_float(u2 << 16);
        ay += __uint_as_float(u2 & 0xffff0000u);
        ax += __uint_as_float(u3 << 16);
        ay += __uint_as_float(u3 & 0xffff0000u);
    }
    for (; k < k1; k++) {
        unsigned u = Hb[(size_t)csr_src[k] * 64 + lane];
        ax += __uint_as_float(u << 16);
        ay += __uint_as_float(u & 0xffff0000u);
    }
    float dt = dinv[row];
    ax *= dt;
    ay *= dt;
    if (bias) {
        float2 b = ((const float2*)bias)[lane];
        ax += b.x;
        ay += b.y;
    }
    ((float2*)OUT)[(size_t)row * 64 + lane] = make_float2(ax, ay);
}

// ---------------- W prep: WT[c][k] = bf16(W[k][c]) for both layers ----------------
__global__ __launch_bounds__(256) void k_wprep(const float* __restrict__ W1,
                                               const float* __restrict__ W2,
                                               unsigned short* __restrict__ WT1,
                                               unsigned short* __restrict__ WT2) {
    int t = blockIdx.x * 256 + threadIdx.x;   // 0..32767
    const float* W = (t < 16384) ? W1 : W2;
    unsigned short* WT = (t < 16384) ? WT1 : WT2;
    int i = t & 16383;
    int k = i >> 7, c = i & 127;
    WT[c * 128 + k] = bf16r(W[k * 128 + c]);
}

// ---------------- MFMA GEMM: Yb = bf16(dinv .* (f(X) @ W)) ----------------
// 64 rows/block, 256 thr (4 waves), wave w owns rows w*16..w*16+15.
// A LDS: [64][AST] bf16 of f(X); B LDS: WT [c][k] padded.
// mfma_f32_16x16x32_bf16: A[m=lane&15][k=quad*8+j], B[k=quad*8+j][n=lane&15],
// C/D col=lane&15, row=quad*4+reg  (verified mappings m89/m120).
// f = identity if sc==null, else relu(x*scale+shift), sc[0:128]=scale,[128:256]=shift
#define AST 136   // bf16 row stride (pad 128+8; 272 B = 17*16, keeps 16B align + banks)
__global__ __launch_bounds__(256) void k_gemm(const float* __restrict__ X,
                                              const unsigned short* __restrict__ WT,
                                              const float* __restrict__ sc,
                                              const float* __restrict__ dinv,
                                              unsigned short* __restrict__ Yb, int n) {
    __shared__ unsigned short Abf[64 * AST];
    __shared__ unsigned short Bbf[128 * AST];
    int tid = threadIdx.x;
    int row0 = blockIdx.x * 64;

    // stage WT -> Bbf: 128 rows x 16 uint4 segs (8 bf16 each)
#pragma unroll
    for (int p = 0; p < 8; p++) {
        int idx = tid + p * 256;
        int c = idx >> 4, s = idx & 15;
        uint4 v = ((const uint4*)(WT + c * 128))[s];
        *(uint4*)&Bbf[c * AST + s * 8] = v;
    }
    // stage f(X) -> Abf bf16: 64 rows x 32 float4 (4 cols each)
#pragma unroll
    for (int p = 0; p < 8; p++) {
        int idx = tid + p * 256;
        int r = idx >> 5, k4 = idx & 31;
        int grow = row0 + r;
        float4 v = make_float4(0.f, 0.f, 0.f, 0.f);
        if (grow < n)
            v = *(const float4*)(X + (size_t)grow * D + k4 * 4);
        if (sc) {
            float4 scl = ((const float4*)sc)[k4];
            float4 sh  = ((const float4*)(sc + D))[k4];
            v.x = fmaxf(fmaf(v.x, scl.x, sh.x), 0.f);
            v.y = fmaxf(fmaf(v.y, scl.y, sh.y), 0.f);
            v.z = fmaxf(fmaf(v.z, scl.z, sh.z), 0.f);
            v.w = fmaxf(fmaf(v.w, scl.w, sh.w), 0.f);
        }
        uint2 pk;
        pk.x = bf16pairp(v.x, v.y);
        pk.y = bf16pairp(v.z, v.w);
        *(uint2*)&Abf[r * AST + k4 * 4] = pk;
    }
    __syncthreads();

    int w = tid >> 6, lane = tid & 63;
    int m = lane & 15, quad = lane >> 4;

    // A fragments for this wave's 16 rows: 4 ksteps
    bf16x8 av[4];
#pragma unroll
    for (int ks = 0; ks < 4; ks++)
        av[ks] = *(const bf16x8*)&Abf[(w * 16 + m) * AST + ks * 32 + quad * 8];

    f32x4 acc[8];
#pragma unroll
    for (int ct = 0; ct < 8; ct++) acc[ct] = (f32x4){0.f, 0.f, 0.f, 0.f};

#pragma unroll
    for (int ct = 0; ct < 8; ct++) {
#pragma unroll
        for (int ks = 0; ks < 4; ks++) {
            bf16x8 bv = *(const bf16x8*)&Bbf[(ct * 16 + m) * AST + ks * 32 + quad * 8];
            acc[ct] = __builtin_amdgcn_mfma_f32_16x16x32_bf16(av[ks], bv, acc[ct], 0, 0, 0);
        }
    }

    // epilogue: row = row0 + w*16 + quad*4 + r, col = ct*16 + m
    float dv[4];
    int rb = row0 + w * 16 + quad * 4;
#pragma unroll
    for (int r = 0; r < 4; r++) dv[r] = (rb + r < n) ? dinv[rb + r] : 0.f;
#pragma unroll
    for (int ct = 0; ct < 8; ct++) {
#pragma unroll
        for (int r = 0; r < 4; r++) {
            int grow = rb + r;
            if (grow < n)
                Yb[(size_t)grow * D + ct * 16 + m] = bf16r(acc[ct][r] * dv[r]);
        }
    }
}

// ---------------- BN stats (512 blocks -> 512-way atomic contention, safe) ----------
__global__ __launch_bounds__(128) void k_bn_stats(const float* __restrict__ A,
                                                  float* __restrict__ sums, int n) {
    int j = threadIdx.x;
    float s = 0.f, ss = 0.f;
    for (int r = blockIdx.x; r < n; r += gridDim.x) {
        float v = A[(size_t)r * D + j];
        s += v;
        ss += v * v;
    }
    atomicAdd(&sums[j], s);
    atomicAdd(&sums[D + j], ss);
}

// sc[0:128]=scale, sc[128:256]=shift.  (b1 cancels exactly in BN — omitted.)
__global__ __launch_bounds__(128) void k_bn_finalize(const float* __restrict__ sums,
                                                     const float* __restrict__ gamma,
                                                     const float* __restrict__ beta,
                                                     float* __restrict__ sc, int n) {
    int j = threadIdx.x;
    float inv_n = 1.0f / (float)n;
    float mu = sums[j] * inv_n;
    float var = sums[D + j] * inv_n - mu * mu;
    float is = rsqrtf(var + BN_EPS);
    float scale = gamma[j] * is;
    sc[j] = scale;
    sc[D + j] = beta[j] - mu * scale;
}

extern "C" void kernel_launch(void* const* d_in, const int* in_sizes, int n_in,
                              void* d_out, int out_size, void* d_ws, size_t ws_size,
                              hipStream_t stream) {
    const float* x     = (const float*)d_in[0];
    const int*   ei    = (const int*)d_in[1];
    const float* W1    = (const float*)d_in[2];
    // d_in[3] = b1 — cancels exactly in BatchNorm, unused
    const float* gamma = (const float*)d_in[4];
    const float* beta  = (const float*)d_in[5];
    const float* W2    = (const float*)d_in[6];
    const float* b2    = (const float*)d_in[7];
    float* out = (float*)d_out;

    int n = in_sizes[0] / D;   // 50000
    int E = in_sizes[1] / 2;   // 800000
    const int* src = ei;
    const int* dst = ei + E;
    int nb = (n + 255) >> 8;          // 196 buckets (must be <= 256)
    int nchunks = (E + CHUNK - 1) / CHUNK;

    char* ws = (char*)d_ws;
    size_t off = 0;
    auto alloc = [&](size_t bytes) {
        char* p = ws + off;
        off = (off + bytes + 511) & ~(size_t)511;
        return p;
    };
    size_t szH = (size_t)n * D * sizeof(float);
    float*          agg    = (float*)alloc(szH);                  // conv1 agg / BN input
    unsigned short* hbf    = (unsigned short*)alloc((size_t)n * D * 2);  // bf16 payload
    float*          dinv   = (float*)alloc(n * sizeof(float));
    int*            rowptr = (int*)alloc((n + 1) * sizeof(int));
    int*            bcnt   = (int*)alloc(256 * sizeof(int));
    int*            bbase  = (int*)alloc(257 * sizeof(int));
    int*            bcur   = (int*)alloc(256 * sizeof(int));
    int2*           bpairs = (int2*)alloc((size_t)E * sizeof(int2));
    int*            csr    = (int*)alloc((size_t)E * sizeof(int));
    unsigned short* wt1    = (unsigned short*)alloc(16384 * 2);
    unsigned short* wt2    = (unsigned short*)alloc(16384 * 2);
    float*          sums   = (float*)alloc(2 * D * sizeof(float));
    float*          sc     = (float*)alloc(2 * D * sizeof(float));

    hipMemsetAsync(bcnt, 0, 256 * sizeof(int), stream);

    // W transpose+bf16 prep (both layers)
    k_wprep<<<128, 256, 0, stream>>>(W1, W2, wt1, wt2);

    // CSR build: bucket hist -> bucket scan (+zero sums) -> pair scatter -> finalize
    k_bhist<<<nchunks, 256, 0, stream>>>(dst, bcnt, E, nb);
    k_bscan<<<1, 256, 0, stream>>>(bcnt, bbase, bcur, sums, nb, E);
    k_bscatter<<<nchunks, 256, 0, stream>>>(src, dst, bcur, bpairs, E, nb);
    k_csr<<<nb, 256, 0, stream>>>(bpairs, bbase, rowptr, csr, dinv, n, nb, E);

    // conv1: hbf = bf16(dinv .* (x@W1)); agg = aggregate(hbf)
    k_gemm<<<(n + 63) / 64, 256, 0, stream>>>(x, wt1, nullptr, dinv, hbf, n);
    k_agg<<<(n + 3) / 4, 256, 0, stream>>>((const unsigned*)hbf, csr, rowptr, dinv,
                                           nullptr, agg, n);

    // BN stats -> scale/shift (ReLU fused into GEMM2 load)
    k_bn_stats<<<512, 128, 0, stream>>>(agg, sums, n);
    k_bn_finalize<<<1, 128, 0, stream>>>(sums, gamma, beta, sc, n);

    // conv2: hbf = bf16(dinv .* (relu(BN(agg))@W2)); out = aggregate(hbf) + b2
    k_gemm<<<(n + 63) / 64, 256, 0, stream>>>(agg, wt2, sc, dinv, hbf, n);
    k_agg<<<(n + 3) / 4, 256, 0, stream>>>((const unsigned*)hbf, csr, rowptr, dinv,
                                           b2, out, n);
}

// Round 10
// 266.503 us; speedup vs baseline: 1.2449x; 1.0386x over previous
//
#include <hip/hip_runtime.h>

#define D 128
#define BN_EPS 1e-5f
#define CHUNK 4096   // edges per block in bucket passes (256 thr x 16)

typedef __attribute__((ext_vector_type(8))) short bf16x8;
typedef __attribute__((ext_vector_type(4))) float f32x4;

// RNE round f32 -> bf16 (returns low 16)
__device__ __forceinline__ unsigned short bf16r(float a) {
    unsigned u = __float_as_uint(a);
    u += 0x7fff + ((u >> 16) & 1);
    return (unsigned short)(u >> 16);
}
// RNE-pack two f32 into bf16 pair (lo = elem0)
__device__ __forceinline__ unsigned bf16pairp(float a, float b) {
    return (unsigned)bf16r(a) | ((unsigned)bf16r(b) << 16);
}

// ---------------- P1: bucket histogram (bucket = dst >> 8) + fused W prep ----------
// Blocks [0, nchunks): histogram. Blocks [nchunks, nchunks+128): WT[c][k]=bf16(W[k][c]).
__global__ __launch_bounds__(256) void k_bhist(const int* __restrict__ dst,
                                               int* __restrict__ bcnt, int E, int nb,
                                               int nchunks,
                                               const float* __restrict__ W1,
                                               const float* __restrict__ W2,
                                               unsigned short* __restrict__ WT1,
                                               unsigned short* __restrict__ WT2) {
    int tid = threadIdx.x;
    if (blockIdx.x >= nchunks) {
        int t = (blockIdx.x - nchunks) * 256 + tid;   // 0..32767
        const float* W = (t < 16384) ? W1 : W2;
        unsigned short* WT = (t < 16384) ? WT1 : WT2;
        int i = t & 16383;
        int k = i >> 7, c = i & 127;
        WT[c * 128 + k] = bf16r(W[k * 128 + c]);
        return;
    }
    __shared__ int h[256];
    h[tid] = 0;
    __syncthreads();
    int base = blockIdx.x * CHUNK + tid;
#pragma unroll
    for (int k = 0; k < 16; k++) {
        int i = base + k * 256;
        if (i < E) atomicAdd(&h[dst[i] >> 8], 1);
    }
    __syncthreads();
    if (tid < nb && h[tid]) atomicAdd(&bcnt[tid], h[tid]);
}

// ---------------- P2: scan bucket counts -> bases + cursors (also zeros sums) --------
__global__ __launch_bounds__(256) void k_bscan(const int* __restrict__ bcnt,
                                               int* __restrict__ bbase,
                                               int* __restrict__ bcur,
                                               float* __restrict__ sums,
                                               int nb, int E) {
    __shared__ int sh[256];
    int tid = threadIdx.x;
    sums[tid] = 0.f;   // 256 floats: colsum + colsumsq for BN
    int v = (tid < nb) ? bcnt[tid] : 0;
    sh[tid] = v;
    __syncthreads();
    for (int off = 1; off < 256; off <<= 1) {
        int u = (tid >= off) ? sh[tid - off] : 0;
        __syncthreads();
        sh[tid] += u;
        __syncthreads();
    }
    if (tid < nb) {
        bbase[tid] = sh[tid] - v;
        bcur[tid] = sh[tid] - v;
    }
    if (tid == 0) bbase[nb] = E;
}

// ---------------- P3: bucket scatter of (src,dst) pairs, run-coalesced ----------------
__global__ __launch_bounds__(256) void k_bscatter(const int* __restrict__ src,
                                                  const int* __restrict__ dst,
                                                  int* __restrict__ bcur,
                                                  int2* __restrict__ bpairs,
                                                  int E, int nb) {
    __shared__ int h[256];
    int tid = threadIdx.x;
    h[tid] = 0;
    __syncthreads();
    int base = blockIdx.x * CHUNK + tid;
    int s[16], t[16], r[16];
#pragma unroll
    for (int k = 0; k < 16; k++) {
        int i = base + k * 256;
        if (i < E) {
            s[k] = src[i];
            t[k] = dst[i];
            r[k] = atomicAdd(&h[t[k] >> 8], 1);
        } else {
            t[k] = -1;
        }
    }
    __syncthreads();
    if (tid < nb) {
        int c = h[tid];
        h[tid] = c ? atomicAdd(&bcur[tid], c) : 0;
    }
    __syncthreads();
#pragma unroll
    for (int k = 0; k < 16; k++) {
        if (t[k] >= 0) bpairs[h[t[k] >> 8] + r[k]] = make_int2(s[k], t[k]);
    }
}

// ---------------- P4: per-bucket CSR finalize (rowptr, dinv, csr) ----------------
__global__ __launch_bounds__(256) void k_csr(const int2* __restrict__ bpairs,
                                             const int* __restrict__ bbase,
                                             int* __restrict__ rowptr,
                                             int* __restrict__ csr,
                                             float* __restrict__ dinv,
                                             int n, int nb, int E) {
    int b = blockIdx.x;
    int tid = threadIdx.x;
    int lo = bbase[b], hi = bbase[b + 1];
    __shared__ int h[256];
    __shared__ int sh[256];
    h[tid] = 0;
    __syncthreads();
    for (int i = lo + tid; i < hi; i += 256) atomicAdd(&h[bpairs[i].y & 255], 1);
    __syncthreads();
    int c = h[tid];
    sh[tid] = c;
    __syncthreads();
    for (int off = 1; off < 256; off <<= 1) {
        int u = (tid >= off) ? sh[tid - off] : 0;
        __syncthreads();
        sh[tid] += u;
        __syncthreads();
    }
    int ex = sh[tid] - c;
    int row = b * 256 + tid;
    if (row < n) {
        rowptr[row] = lo + ex;
        dinv[row] = rsqrtf((float)(c + 1));   // +1 = self loop
    }
    if (b == 0 && tid == 0) rowptr[n] = E;
    __syncthreads();
    h[tid] = lo + ex;   // reuse as cursor
    __syncthreads();
    for (int i = lo + tid; i < hi; i += 256) {
        int2 p = bpairs[i];
        int pos = atomicAdd(&h[p.y & 255], 1);
        csr[pos] = p.x;
    }
}

// ---------------- slot-gather aggregation: one wave per row, 4 edges/instr ----------
// Lane L: slot = L>>4 (which of 4 concurrent edges), seg = L&15 (16 B segment of row).
// Hb row = 128 bf16 = 16 uint4 segs. One gather instr fetches 4 edges' rows.
// acc[8] = cols seg*8..seg*8+7 for this slot's edges; butterfly (xor16,32) combines.
// OUT[t] = ( Hb[t] + sum_{s in N(t)} Hb[s] ) * dinv[t] + bias   (payload pre-scaled)
__device__ __forceinline__ void unpack_add(uint4 u, float* acc) {
    acc[0] += __uint_as_float(u.x << 16);
    acc[1] += __uint_as_float(u.x & 0xffff0000u);
    acc[2] += __uint_as_float(u.y << 16);
    acc[3] += __uint_as_float(u.y & 0xffff0000u);
    acc[4] += __uint_as_float(u.z << 16);
    acc[5] += __uint_as_float(u.z & 0xffff0000u);
    acc[6] += __uint_as_float(u.w << 16);
    acc[7] += __uint_as_float(u.w & 0xffff0000u);
}

__global__ __launch_bounds__(256) void k_agg(const unsigned short* __restrict__ Hb,
                                             const int* __restrict__ csr_src,
                                             const int* __restrict__ rowptr,
                                             const float* __restrict__ dinv,
                                             const float* __restrict__ bias,
                                             float* __restrict__ OUT, int n) {
    int row = blockIdx.x * 4 + (threadIdx.x >> 6);
    if (row >= n) return;
    int lane = threadIdx.x & 63;
    int slot = lane >> 4, seg = lane & 15;
    const uint4* HB4 = (const uint4*)Hb;

    float acc[8];
#pragma unroll
    for (int i = 0; i < 8; i++) acc[i] = 0.f;
    if (slot == 0) {                       // self term once
        uint4 us = HB4[(size_t)row * 16 + seg];
        unpack_add(us, acc);
    }

    int k0 = rowptr[row], k1 = rowptr[row + 1];
    int deg = k1 - k0;
    int iters = deg >> 2;
    int k = k0 + slot;
    int it = 0;
    for (; it + 4 <= iters; it += 4, k += 16) {
        int s0 = csr_src[k], s1 = csr_src[k + 4];
        int s2 = csr_src[k + 8], s3 = csr_src[k + 12];
        uint4 u0 = HB4[(size_t)s0 * 16 + seg];
        uint4 u1 = HB4[(size_t)s1 * 16 + seg];
        uint4 u2 = HB4[(size_t)s2 * 16 + seg];
        uint4 u3 = HB4[(size_t)s3 * 16 + seg];
        unpack_add(u0, acc);
        unpack_add(u1, acc);
        unpack_add(u2, acc);
        unpack_add(u3, acc);
    }
    for (; it < iters; it++, k += 4) {
        int s = csr_src[k];
        uint4 u = HB4[(size_t)s * 16 + seg];
        unpack_add(u, acc);
    }
    if (slot < (deg & 3)) {                // tail edges
        int s = csr_src[k];
        uint4 u = HB4[(size_t)s * 16 + seg];
        unpack_add(u, acc);
    }

    // combine 4 slots
#pragma unroll
    for (int i = 0; i < 8; i++) {
        acc[i] += __shfl_xor(acc[i], 16, 64);
        acc[i] += __shfl_xor(acc[i], 32, 64);
    }

    float dt = dinv[row];
    float v0 = acc[slot * 2] * dt;
    float v1 = acc[slot * 2 + 1] * dt;
    int cp = seg * 4 + slot;               // float2 index = col/2
    if (bias) {
        float2 b = ((const float2*)bias)[cp];
        v0 += b.x;
        v1 += b.y;
    }
    ((float2*)OUT)[(size_t)row * 64 + cp] = make_float2(v0, v1);
}

// ---------------- MFMA GEMM: Yb = bf16(dinv .* (f(X) @ W)) ----------------
// 64 rows/block, 256 thr (4 waves), wave w owns rows w*16..w*16+15.
// mfma_f32_16x16x32_bf16: A[m=lane&15][k=quad*8+j], B[k][n=lane&15],
// C/D col=lane&15, row=quad*4+reg  (verified mappings m89/m120).
// f = identity if sc==null, else relu(x*scale+shift), sc[0:128]=scale,[128:256]=shift
#define AST 136   // bf16 row stride (pad 128+8)
__global__ __launch_bounds__(256) void k_gemm(const float* __restrict__ X,
                                              const unsigned short* __restrict__ WT,
                                              const float* __restrict__ sc,
                                              const float* __restrict__ dinv,
                                              unsigned short* __restrict__ Yb, int n) {
    __shared__ unsigned short Abf[64 * AST];
    __shared__ unsigned short Bbf[128 * AST];
    int tid = threadIdx.x;
    int row0 = blockIdx.x * 64;

    // stage WT -> Bbf: 128 rows x 16 uint4 segs (8 bf16 each)
#pragma unroll
    for (int p = 0; p < 8; p++) {
        int idx = tid + p * 256;
        int c = idx >> 4, s = idx & 15;
        uint4 v = ((const uint4*)(WT + c * 128))[s];
        *(uint4*)&Bbf[c * AST + s * 8] = v;
    }
    // stage f(X) -> Abf bf16: 64 rows x 32 float4 (4 cols each)
#pragma unroll
    for (int p = 0; p < 8; p++) {
        int idx = tid + p * 256;
        int r = idx >> 5, k4 = idx & 31;
        int grow = row0 + r;
        float4 v = make_float4(0.f, 0.f, 0.f, 0.f);
        if (grow < n)
            v = *(const float4*)(X + (size_t)grow * D + k4 * 4);
        if (sc) {
            float4 scl = ((const float4*)sc)[k4];
            float4 sh  = ((const float4*)(sc + D))[k4];
            v.x = fmaxf(fmaf(v.x, scl.x, sh.x), 0.f);
            v.y = fmaxf(fmaf(v.y, scl.y, sh.y), 0.f);
            v.z = fmaxf(fmaf(v.z, scl.z, sh.z), 0.f);
            v.w = fmaxf(fmaf(v.w, scl.w, sh.w), 0.f);
        }
        uint2 pk;
        pk.x = bf16pairp(v.x, v.y);
        pk.y = bf16pairp(v.z, v.w);
        *(uint2*)&Abf[r * AST + k4 * 4] = pk;
    }
    __syncthreads();

    int w = tid >> 6, lane = tid & 63;
    int m = lane & 15, quad = lane >> 4;

    bf16x8 av[4];
#pragma unroll
    for (int ks = 0; ks < 4; ks++)
        av[ks] = *(const bf16x8*)&Abf[(w * 16 + m) * AST + ks * 32 + quad * 8];

    f32x4 acc[8];
#pragma unroll
    for (int ct = 0; ct < 8; ct++) acc[ct] = (f32x4){0.f, 0.f, 0.f, 0.f};

#pragma unroll
    for (int ct = 0; ct < 8; ct++) {
#pragma unroll
        for (int ks = 0; ks < 4; ks++) {
            bf16x8 bv = *(const bf16x8*)&Bbf[(ct * 16 + m) * AST + ks * 32 + quad * 8];
            acc[ct] = __builtin_amdgcn_mfma_f32_16x16x32_bf16(av[ks], bv, acc[ct], 0, 0, 0);
        }
    }

    float dv[4];
    int rb = row0 + w * 16 + quad * 4;
#pragma unroll
    for (int r = 0; r < 4; r++) dv[r] = (rb + r < n) ? dinv[rb + r] : 0.f;
#pragma unroll
    for (int ct = 0; ct < 8; ct++) {
#pragma unroll
        for (int r = 0; r < 4; r++) {
            int grow = rb + r;
            if (grow < n)
                Yb[(size_t)grow * D + ct * 16 + m] = bf16r(acc[ct][r] * dv[r]);
        }
    }
}

// ---------------- BN stats (512 blocks -> 512-way atomic contention, safe) ----------
__global__ __launch_bounds__(128) void k_bn_stats(const float* __restrict__ A,
                                                  float* __restrict__ sums, int n) {
    int j = threadIdx.x;
    float s = 0.f, ss = 0.f;
    for (int r = blockIdx.x; r < n; r += gridDim.x) {
        float v = A[(size_t)r * D + j];
        s += v;
        ss += v * v;
    }
    atomicAdd(&sums[j], s);
    atomicAdd(&sums[D + j], ss);
}

// sc[0:128]=scale, sc[128:256]=shift.  (b1 cancels exactly in BN — omitted.)
__global__ __launch_bounds__(128) void k_bn_finalize(const float* __restrict__ sums,
                                                     const float* __restrict__ gamma,
                                                     const float* __restrict__ beta,
                                                     float* __restrict__ sc, int n) {
    int j = threadIdx.x;
    float inv_n = 1.0f / (float)n;
    float mu = sums[j] * inv_n;
    float var = sums[D + j] * inv_n - mu * mu;
    float is = rsqrtf(var + BN_EPS);
    float scale = gamma[j] * is;
    sc[j] = scale;
    sc[D + j] = beta[j] - mu * scale;
}

extern "C" void kernel_launch(void* const* d_in, const int* in_sizes, int n_in,
                              void* d_out, int out_size, void* d_ws, size_t ws_size,
                              hipStream_t stream) {
    const float* x     = (const float*)d_in[0];
    const int*   ei    = (const int*)d_in[1];
    const float* W1    = (const float*)d_in[2];
    // d_in[3] = b1 — cancels exactly in BatchNorm, unused
    const float* gamma = (const float*)d_in[4];
    const float* beta  = (const float*)d_in[5];
    const float* W2    = (const float*)d_in[6];
    const float* b2    = (const float*)d_in[7];
    float* out = (float*)d_out;

    int n = in_sizes[0] / D;   // 50000
    int E = in_sizes[1] / 2;   // 800000
    const int* src = ei;
    const int* dst = ei + E;
    int nb = (n + 255) >> 8;          // 196 buckets (must be <= 256)
    int nchunks = (E + CHUNK - 1) / CHUNK;

    char* ws = (char*)d_ws;
    size_t off = 0;
    auto alloc = [&](size_t bytes) {
        char* p = ws + off;
        off = (off + bytes + 511) & ~(size_t)511;
        return p;
    };
    size_t szH = (size_t)n * D * sizeof(float);
    float*          agg    = (float*)alloc(szH);                  // conv1 agg / BN input
    unsigned short* hbf    = (unsigned short*)alloc((size_t)n * D * 2);  // bf16 payload
    float*          dinv   = (float*)alloc(n * sizeof(float));
    int*            rowptr = (int*)alloc((n + 1) * sizeof(int));
    int*            bcnt   = (int*)alloc(256 * sizeof(int));
    int*            bbase  = (int*)alloc(257 * sizeof(int));
    int*            bcur   = (int*)alloc(256 * sizeof(int));
    int2*           bpairs = (int2*)alloc((size_t)E * sizeof(int2));
    int*            csr    = (int*)alloc((size_t)E * sizeof(int));
    unsigned short* wt1    = (unsigned short*)alloc(16384 * 2);
    unsigned short* wt2    = (unsigned short*)alloc(16384 * 2);
    float*          sums   = (float*)alloc(2 * D * sizeof(float));
    float*          sc     = (float*)alloc(2 * D * sizeof(float));

    hipMemsetAsync(bcnt, 0, 256 * sizeof(int), stream);

    // CSR build (+fused W prep): hist -> scan (+zero sums) -> pair scatter -> finalize
    k_bhist<<<nchunks + 128, 256, 0, stream>>>(dst, bcnt, E, nb, nchunks,
                                               W1, W2, wt1, wt2);
    k_bscan<<<1, 256, 0, stream>>>(bcnt, bbase, bcur, sums, nb, E);
    k_bscatter<<<nchunks, 256, 0, stream>>>(src, dst, bcur, bpairs, E, nb);
    k_csr<<<nb, 256, 0, stream>>>(bpairs, bbase, rowptr, csr, dinv, n, nb, E);

    // conv1: hbf = bf16(dinv .* (x@W1)); agg = aggregate(hbf)
    k_gemm<<<(n + 63) / 64, 256, 0, stream>>>(x, wt1, nullptr, dinv, hbf, n);
    k_agg<<<(n + 3) / 4, 256, 0, stream>>>(hbf, csr, rowptr, dinv, nullptr, agg, n);

    // BN stats -> scale/shift (ReLU fused into GEMM2 load)
    k_bn_stats<<<512, 128, 0, stream>>>(agg, sums, n);
    k_bn_finalize<<<1, 128, 0, stream>>>(sums, gamma, beta, sc, n);

    // conv2: hbf = bf16(dinv .* (relu(BN(agg))@W2)); out = aggregate(hbf) + b2
    k_gemm<<<(n + 63) / 64, 256, 0, stream>>>(agg, wt2, sc, dinv, hbf, n);
    k_agg<<<(n + 3) / 4, 256, 0, stream>>>(hbf, csr, rowptr, dinv, b2, out, n);
}